// Round 2
// baseline (385.346 us; speedup 1.0000x reference)
//
#include <hip/hip_runtime.h>
#include <hip/hip_bf16.h>
#include <stdint.h>

// Problem constants (from reference setup_inputs)
#define BB   64
#define SS   2048
#define DD   512
#define NBLK 8

typedef unsigned short u16;
typedef unsigned int   u32;

// ---- bf16 -> f32 helpers (exact bit ops) ----
__device__ __forceinline__ float lo2f(u32 u) {
    union { u32 i; float f; } v; v.i = u << 16; return v.f;
}
__device__ __forceinline__ float hi2f(u32 u) {
    union { u32 i; float f; } v; v.i = u & 0xffff0000u; return v.f;
}

// load 8 consecutive elements (element offset `off`) as f32
template<bool BF16>
__device__ __forceinline__ void load8(const void* base, size_t off, float* o) {
    if (BF16) {
        const uint4 v = *(const uint4*)((const u16*)base + off);
        o[0]=lo2f(v.x); o[1]=hi2f(v.x); o[2]=lo2f(v.y); o[3]=hi2f(v.y);
        o[4]=lo2f(v.z); o[5]=hi2f(v.z); o[6]=lo2f(v.w); o[7]=hi2f(v.w);
    } else {
        const float4* p = (const float4*)((const float*)base + off);
        const float4 a = p[0], b = p[1];
        o[0]=a.x; o[1]=a.y; o[2]=a.z; o[3]=a.w;
        o[4]=b.x; o[5]=b.y; o[6]=b.z; o[7]=b.w;
    }
}

template<bool BF16>
__device__ __forceinline__ float load1(const void* base, size_t idx) {
    if (BF16) return lo2f(((const u16*)base)[idx]);
    else      return ((const float*)base)[idx];
}

template<bool BF16>
__device__ __forceinline__ void store_out(void* base, size_t idx, float v) {
    if (BF16) ((__hip_bfloat16*)base)[idx] = __float2bfloat16(v);
    else      ((float*)base)[idx] = v;
}

// target accessors: TGT_WS -> f32 in workspace; else OutT in d_out wc region
template<bool BF16, bool TGT_WS>
__device__ __forceinline__ void load_tgt8(const void* tgt, size_t off, float* o) {
    if (TGT_WS) {
        const float4* p = (const float4*)((const float*)tgt + off);
        const float4 a = p[0], b = p[1];
        o[0]=a.x; o[1]=a.y; o[2]=a.z; o[3]=a.w;
        o[4]=b.x; o[5]=b.y; o[6]=b.z; o[7]=b.w;
    } else {
        load8<BF16>(tgt, off, o);
    }
}
template<bool BF16, bool TGT_WS>
__device__ __forceinline__ void store_tgt(void* tgt, size_t idx, float v) {
    if (TGT_WS) ((float*)tgt)[idx] = v;
    else        store_out<BF16>(tgt, idx, v);
}

__device__ __forceinline__ float dot8f(const float* a, const float* t) {
    float acc = a[0] * t[0];
    #pragma unroll
    for (int i = 1; i < 8; ++i) acc = fmaf(a[i], t[i], acc);
    return acc;
}

__device__ __forceinline__ float wave_reduce_sum(float acc) {
    #pragma unroll
    for (int off = 32; off >= 1; off >>= 1)
        acc += __shfl_xor(acc, off, 64);
    return acc;
}

// ---------------------------------------------------------------------
// K0: dtype sniff. f32 words have uniform low-16 bits; bf16-pair words
// have a bf16 exponent field (bits 14:7) concentrated near 127 for
// N(0,1) data. Majority vote over 64 sampled words. flag=1 -> bf16.
// ---------------------------------------------------------------------
__global__ void k0_sniff(const u32* __restrict__ ctx_w, int* __restrict__ flag) {
    const int lane = threadIdx.x;                 // 64 threads
    const u32 w = ctx_w[(size_t)lane * 997];
    const u32 e = (w >> 7) & 0xFF;                // low-u16 "exponent" field
    int ok = (e >= 100 && e <= 135) ? 1 : 0;
    #pragma unroll
    for (int off = 32; off >= 1; off >>= 1)
        ok += __shfl_xor(ok, off, 64);
    if (lane == 0) *flag = (ok >= 32) ? 1 : 0;
}

// ---------------------------------------------------------------------
// K1: target[b,i] = sum_k h[b,k] * W[i,k]  (h @ W.T)
// One wave computes 4 outputs (reuses the h fragment).
// ---------------------------------------------------------------------
#define K1_IPW 4
template<bool BF16, bool TGT_WS>
__global__ __launch_bounds__(256) void k1_target(
        const void* __restrict__ h, const void* __restrict__ W,
        void* __restrict__ tgt, const int* __restrict__ flag) {
    if ((*flag != 0) != BF16) return;
    const int wid  = (blockIdx.x * blockDim.x + threadIdx.x) >> 6;
    const int lane = threadIdx.x & 63;
    const int out0 = wid * K1_IPW;          // global index = b*DD + i
    const int b    = out0 / DD;
    const int i0   = out0 - b * DD;

    float hf[8];
    load8<BF16>(h, (size_t)b * DD + lane * 8, hf);

    #pragma unroll
    for (int r = 0; r < K1_IPW; ++r) {
        const int i = i0 + r;
        float wf[8];
        load8<BF16>(W, (size_t)i * DD + lane * 8, wf);
        float acc = dot8f(wf, hf);
        acc = wave_reduce_sum(acc);
        if (lane == 0) store_tgt<BF16, TGT_WS>(tgt, (size_t)b * DD + i, acc);
    }
}

// ---------------------------------------------------------------------
// K2: attn[b,s] = context[b,s,:] . target[b,:]  -> OutT to d_out.
// One row per wave iteration (64 lanes x 8 elems = full 512-row).
// ---------------------------------------------------------------------
#define K2_RPW 8
template<bool BF16, bool TGT_WS>
__global__ __launch_bounds__(256) void k2_attn(
        const void* __restrict__ ctx, const void* __restrict__ tgt,
        void* __restrict__ dout, const int* __restrict__ flag) {
    if ((*flag != 0) != BF16) return;
    void* attn_out = BF16 ? (void*)((u16*)dout + (size_t)BB * DD)
                          : (void*)((float*)dout + (size_t)BB * DD);

    const int wid  = (blockIdx.x * blockDim.x + threadIdx.x) >> 6;
    const int lane = threadIdx.x & 63;
    const size_t row0 = (size_t)wid * K2_RPW;   // global row = b*SS + s
    const int b = (int)(row0 >> 11);            // / SS

    float t[8];
    load_tgt8<BF16, TGT_WS>(tgt, (size_t)b * DD + lane * 8, t);

    const size_t cbase = row0 * DD + (size_t)lane * 8;
    float keep = 0.f;
    #pragma unroll
    for (int r = 0; r < K2_RPW; ++r) {
        float cf[8];
        load8<BF16>(ctx, cbase + (size_t)r * DD, cf);
        float acc = dot8f(cf, t);
        acc = wave_reduce_sum(acc);
        if (lane == r) keep = acc;   // lane r keeps row r's result
    }
    if (lane < K2_RPW)
        store_out<BF16>(attn_out, row0 + lane, keep);
}

// ---------------------------------------------------------------------
// K3: per batch: block bounds, f32 block logits, softmax, weighted sum.
// One 256-thread block per batch element. In TGT_WS=false mode the
// target lives in the wc region of d_out: all waves read it at kernel
// entry, wc writes happen only in the final phase (after syncthreads),
// and only block b touches slice b -> no hazard.
// ---------------------------------------------------------------------
template<bool BF16, bool TGT_WS>
__global__ __launch_bounds__(256) void k3_softmax_wc(
        const void* __restrict__ ctx, const void* __restrict__ tgt,
        const int* __restrict__ lens, const int* __restrict__ sel,
        void* __restrict__ dout, const int* __restrict__ flag) {
    if ((*flag != 0) != BF16) return;
    const int b    = blockIdx.x;
    const int tid  = threadIdx.x;
    const int lane = tid & 63;
    const int wave = tid >> 6;

    __shared__ float attn_s[64];
    __shared__ float p_s[64];

    // selected-block boundaries: sc = (excl-cumsum at sel) + 1, L = lens[sel]
    const int sidx = sel[b];
    int start = 0;
    #pragma unroll
    for (int j = 0; j < NBLK; ++j) {
        int lj = lens[b * NBLK + j];
        if (j < sidx) start += lj;
    }
    const int L  = lens[b * NBLK + sidx];   // 1..63
    const int sc = start + 1;

    float t[8];
    load_tgt8<BF16, TGT_WS>(tgt, (size_t)b * DD + lane * 8, t);

    // f32 logits for the selected block rows (wave-parallel over rows)
    for (int s = wave; s < L; s += 4) {
        float cf[8];
        load8<BF16>(ctx, ((size_t)b * SS + sc + s) * DD + lane * 8, cf);
        float acc = dot8f(cf, t);
        acc = wave_reduce_sum(acc);
        if (lane == 0) attn_s[s] = acc;
    }
    __syncthreads();

    // softmax over L values (single wave; L <= 63)
    if (tid < 64) {
        const float v = (tid < L) ? attn_s[tid] : -INFINITY;
        float m = v;
        #pragma unroll
        for (int off = 32; off >= 1; off >>= 1)
            m = fmaxf(m, __shfl_xor(m, off, 64));
        const float e = (tid < L) ? __expf(v - m) : 0.f;
        float sum = e;
        #pragma unroll
        for (int off = 32; off >= 1; off >>= 1)
            sum += __shfl_xor(sum, off, 64);
        p_s[tid] = e / sum;
    }
    __syncthreads();

    // weighted_context[b,d] = sum_s p[s] * ctx[b, sc+s, d]
    #pragma unroll
    for (int rep = 0; rep < 2; ++rep) {
        const int d = tid + rep * 256;
        float acc = 0.f;
        for (int s = 0; s < L; ++s)
            acc = fmaf(p_s[s], load1<BF16>(ctx, ((size_t)b * SS + sc + s) * DD + d), acc);
        store_out<BF16>(dout, (size_t)b * DD + d, acc);
    }
}

// ---------------------------------------------------------------------
extern "C" void kernel_launch(void* const* d_in, const int* in_sizes, int n_in,
                              void* d_out, int out_size, void* d_ws, size_t ws_size,
                              hipStream_t stream) {
    const void* h    = d_in[0];              // [B, D]
    const void* ctx  = d_in[1];              // [B, S, D]
    const void* W    = d_in[2];              // [D, D]
    const int* lens  = (const int*)d_in[3];  // [B, NB] i32
    const int* sel   = (const int*)d_in[4];  // [B]     i32

    int* flag = (int*)d_ws;                                  // ws[0:4)
    float* tgt_ws = (float*)((char*)d_ws + 256);             // B*D f32 = 128 KiB
    const bool use_ws = (ws_size >= 256 + (size_t)BB * DD * 4);

    k0_sniff<<<1, 64, 0, stream>>>((const u32*)ctx, flag);

    const int g1 = (BB * DD / K1_IPW) / 4;   // 4 waves/block, K1_IPW outs/wave
    const int g2 = (BB * SS / K2_RPW) / 4;

    if (use_ws) {
        k1_target<true , true ><<<g1, 256, 0, stream>>>(h, W, tgt_ws, flag);
        k1_target<false, true ><<<g1, 256, 0, stream>>>(h, W, tgt_ws, flag);
        k2_attn  <true , true ><<<g2, 256, 0, stream>>>(ctx, tgt_ws, d_out, flag);
        k2_attn  <false, true ><<<g2, 256, 0, stream>>>(ctx, tgt_ws, d_out, flag);
        k3_softmax_wc<true , true ><<<BB, 256, 0, stream>>>(ctx, tgt_ws, lens, sel, d_out, flag);
        k3_softmax_wc<false, true ><<<BB, 256, 0, stream>>>(ctx, tgt_ws, lens, sel, d_out, flag);
    } else {
        // target lives (in output dtype) in the wc region of d_out,
        // overwritten by K3's wc writes afterwards.
        k1_target<true , false><<<g1, 256, 0, stream>>>(h, W, d_out, flag);
        k1_target<false, false><<<g1, 256, 0, stream>>>(h, W, d_out, flag);
        k2_attn  <true , false><<<g2, 256, 0, stream>>>(ctx, d_out, d_out, flag);
        k2_attn  <false, false><<<g2, 256, 0, stream>>>(ctx, d_out, d_out, flag);
        k3_softmax_wc<true , false><<<BB, 256, 0, stream>>>(ctx, d_out, lens, sel, d_out, flag);
        k3_softmax_wc<false, false><<<BB, 256, 0, stream>>>(ctx, d_out, lens, sel, d_out, flag);
    }
}

// Round 5
// 377.471 us; speedup vs baseline: 1.0209x; 1.0209x over previous
//
#include <hip/hip_runtime.h>
#include <hip/hip_bf16.h>
#include <stdint.h>

// Problem constants (from reference setup_inputs)
//
// Dtype facts — established by controlled comparison R1..R4:
//   inputs  = float32  (bf16-read kernels NaN via Inf-Inf; R4's f32 reads
//                       gave finite values)
//   outputs = float32  (R4 wrote bf16 and the harness's f32 readback showed
//                       the exact predicted signature: attn-as-bf16-pairs in
//                       Output0's tail (err 96.7 ~ max|N(0,22)| over 2^15)
//                       and zeros beyond my written bytes (err 454.0 =
//                       max|attn_ref|). R2 passed through store_out<false>,
//                       which stores f32.)
//   The "(bf16, ref=np)" in the test log is a hard-coded f-string, not a
//   dtype probe. Threshold 2.14 comes from the harness's bf16-grade floor.
#define BB   64
#define SS   2048
#define DD   512
#define NBLK 8

// load 8 consecutive f32 (two float4s); p must be 16B-aligned
__device__ __forceinline__ void load8f(const float* __restrict__ p, float* o) {
    const float4 a = ((const float4*)p)[0];
    const float4 b = ((const float4*)p)[1];
    o[0]=a.x; o[1]=a.y; o[2]=a.z; o[3]=a.w;
    o[4]=b.x; o[5]=b.y; o[6]=b.z; o[7]=b.w;
}

__device__ __forceinline__ float dot8f(const float* a, const float* t) {
    float acc = a[0] * t[0];
    #pragma unroll
    for (int i = 1; i < 8; ++i) acc = fmaf(a[i], t[i], acc);
    return acc;
}

__device__ __forceinline__ float wave_reduce_sum(float acc) {
    #pragma unroll
    for (int off = 32; off >= 1; off >>= 1)
        acc += __shfl_xor(acc, off, 64);
    return acc;
}

// ---------------------------------------------------------------------
// K1: target[b,i] = sum_k h[b,k] * W[i,k]  (h @ W.T), f32 -> tgt (ws).
// One wave computes 4 outputs; pairwise-fold reduction: 7 shfl / 4 rows.
// ---------------------------------------------------------------------
#define K1_IPW 4
__global__ __launch_bounds__(256) void sdba_k1_target(
        const float* __restrict__ h, const float* __restrict__ W,
        float* __restrict__ tgt) {
    const int wid  = (blockIdx.x * blockDim.x + threadIdx.x) >> 6;
    const int lane = threadIdx.x & 63;
    const int out0 = wid * K1_IPW;          // global index = b*DD + i0
    const int b    = out0 / DD;
    const int i0   = out0 - b * DD;

    float hf[8];
    load8f(h + (size_t)b * DD + lane * 8, hf);

    float acc[K1_IPW];
    #pragma unroll
    for (int r = 0; r < K1_IPW; ++r) {
        float wf[8];
        load8f(W + (size_t)(i0 + r) * DD + lane * 8, wf);
        acc[r] = dot8f(wf, hf);
    }

    // fold rows across lane bits 0..1; lane ends holding row (lane&3)
    float b2[2];
    {
        const int bit = lane & 1;
        #pragma unroll
        for (int j = 0; j < 2; ++j) {
            float keep = bit ? acc[2*j+1] : acc[2*j];
            float send = bit ? acc[2*j]   : acc[2*j+1];
            b2[j] = keep + __shfl_xor(send, 1, 64);
        }
    }
    float v;
    {
        const int bit = (lane >> 1) & 1;
        float keep = bit ? b2[1] : b2[0];
        float send = bit ? b2[0] : b2[1];
        v = keep + __shfl_xor(send, 2, 64);
    }
    v += __shfl_xor(v, 4, 64);
    v += __shfl_xor(v, 8, 64);
    v += __shfl_xor(v, 16, 64);
    v += __shfl_xor(v, 32, 64);

    if (lane < K1_IPW)
        tgt[(size_t)out0 + lane] = v;
}

// ---------------------------------------------------------------------
// K2: attn[b,s] = context[b,s,:] . target[b,:]  -> f32 to d_out.
// 8 rows per wave; 64 lanes x 32B = one full 2 KiB f32 row per iter.
// Pairwise-fold reduction: 10 shfl / 8 rows (vs 48 independent).
// ---------------------------------------------------------------------
#define K2_RPW 8
__global__ __launch_bounds__(256) void sdba_k2_attn(
        const float* __restrict__ ctx, const float* __restrict__ tgt,
        float* __restrict__ attn_out) {
    const int wid  = (blockIdx.x * blockDim.x + threadIdx.x) >> 6;
    const int lane = threadIdx.x & 63;
    const size_t row0 = (size_t)wid * K2_RPW;   // global row = b*SS + s
    const int b = (int)(row0 >> 11);            // / SS (2048)

    float t[8];
    load8f(tgt + (size_t)b * DD + lane * 8, t);

    const float* cbase = ctx + row0 * DD + (size_t)lane * 8;
    float acc[K2_RPW];
    #pragma unroll
    for (int r = 0; r < K2_RPW; ++r) {
        float cf[8];
        load8f(cbase + (size_t)r * DD, cf);
        acc[r] = dot8f(cf, t);
    }

    // fold rows across lane bits 0..2; lane ends holding row (lane&7)
    float b4[4];
    {
        const int bit = lane & 1;
        #pragma unroll
        for (int j = 0; j < 4; ++j) {
            float keep = bit ? acc[2*j+1] : acc[2*j];
            float send = bit ? acc[2*j]   : acc[2*j+1];
            b4[j] = keep + __shfl_xor(send, 1, 64);
        }
    }
    float b2[2];
    {
        const int bit = (lane >> 1) & 1;
        #pragma unroll
        for (int j = 0; j < 2; ++j) {
            float keep = bit ? b4[2*j+1] : b4[2*j];
            float send = bit ? b4[2*j]   : b4[2*j+1];
            b2[j] = keep + __shfl_xor(send, 2, 64);
        }
    }
    float v;
    {
        const int bit = (lane >> 2) & 1;
        float keep = bit ? b2[1] : b2[0];
        float send = bit ? b2[0] : b2[1];
        v = keep + __shfl_xor(send, 4, 64);
    }
    v += __shfl_xor(v, 8, 64);
    v += __shfl_xor(v, 16, 64);
    v += __shfl_xor(v, 32, 64);

    if (lane < K2_RPW)
        attn_out[row0 + lane] = v;
}

// ---------------------------------------------------------------------
// K3: per batch: block bounds, block logits, softmax, weighted sum.
// One 256-thread block per batch element. All f32.
// ---------------------------------------------------------------------
__global__ __launch_bounds__(256) void sdba_k3_softmax_wc(
        const float* __restrict__ ctx, const float* __restrict__ tgt,
        const int* __restrict__ lens, const int* __restrict__ sel,
        float* __restrict__ out_wc) {
    const int b    = blockIdx.x;
    const int tid  = threadIdx.x;
    const int lane = tid & 63;
    const int wave = tid >> 6;

    __shared__ float attn_s[64];
    __shared__ float p_s[64];
    __shared__ float red[4][DD];   // 8 KiB cross-wave reduction buffer

    // selected-block boundaries: sc = excl-cumsum at sel + 1, L = lens[sel]
    const int sidx = sel[b];
    int start = 0;
    #pragma unroll
    for (int j = 0; j < NBLK; ++j) {
        int lj = lens[b * NBLK + j];
        if (j < sidx) start += lj;
    }
    const int L  = lens[b * NBLK + sidx];   // 1..63
    const int sc = start + 1;

    float t[8];
    load8f(tgt + (size_t)b * DD + lane * 8, t);

    // logits for the selected block rows (wave-parallel over rows)
    for (int s = wave; s < L; s += 4) {
        float cf[8];
        load8f(ctx + ((size_t)b * SS + sc + s) * DD + lane * 8, cf);
        float acc = dot8f(cf, t);
        acc = wave_reduce_sum(acc);
        if (lane == 0) attn_s[s] = acc;
    }
    __syncthreads();

    // softmax over L values (single wave; L <= 63)
    if (tid < 64) {
        const float v = (tid < L) ? attn_s[tid] : -INFINITY;
        float m = v;
        #pragma unroll
        for (int off = 32; off >= 1; off >>= 1)
            m = fmaxf(m, __shfl_xor(m, off, 64));
        const float e = (tid < L) ? __expf(v - m) : 0.f;
        float sum = e;
        #pragma unroll
        for (int off = 32; off >= 1; off >>= 1)
            sum += __shfl_xor(sum, off, 64);
        p_s[tid] = e / sum;
    }
    __syncthreads();

    // weighted_context[b,d] = sum_s p[s] * ctx[b, sc+s, d]
    // rows striped over 4 waves, 8 f32/lane, LDS cross-wave reduce
    float acc[8] = {0,0,0,0,0,0,0,0};
    for (int s = wave; s < L; s += 4) {
        float cf[8];
        load8f(ctx + ((size_t)b * SS + sc + s) * DD + lane * 8, cf);
        const float ps = p_s[s];
        #pragma unroll
        for (int j = 0; j < 8; ++j)
            acc[j] = fmaf(ps, cf[j], acc[j]);
    }
    #pragma unroll
    for (int j = 0; j < 8; ++j)
        red[wave][lane * 8 + j] = acc[j];
    __syncthreads();

    #pragma unroll
    for (int rep = 0; rep < 2; ++rep) {
        const int d = tid + rep * 256;
        const float v = red[0][d] + red[1][d] + red[2][d] + red[3][d];
        out_wc[(size_t)b * DD + d] = v;
    }
}

// ---------------------------------------------------------------------
extern "C" void kernel_launch(void* const* d_in, const int* in_sizes, int n_in,
                              void* d_out, int out_size, void* d_ws, size_t ws_size,
                              hipStream_t stream) {
    const float* h   = (const float*)d_in[0];  // [B, D]    f32
    const float* ctx = (const float*)d_in[1];  // [B, S, D] f32
    const float* W   = (const float*)d_in[2];  // [D, D]    f32
    const int* lens  = (const int*)d_in[3];    // [B, NB]   i32
    const int* sel   = (const int*)d_in[4];    // [B]       i32

    float* out      = (float*)d_out;           // wc [B,D] then attn [B,S], f32
    float* attn_out = out + (size_t)BB * DD;

    // target scratch: B*D f32 = 128 KiB in ws (ws is ~1 GiB; fallback uses
    // the wc region of d_out, overwritten by K3 afterwards)
    float* tgt = (ws_size >= (size_t)BB * DD * 4) ? (float*)d_ws : out;

    const int g1 = (BB * DD / K1_IPW) / 4;   // 2048 blocks (4 waves/block)
    const int g2 = (BB * SS / K2_RPW) / 4;   // 4096 blocks

    sdba_k1_target<<<g1, 256, 0, stream>>>(h, W, tgt);
    sdba_k2_attn<<<g2, 256, 0, stream>>>(ctx, tgt, attn_out);
    sdba_k3_softmax_wc<<<BB, 256, 0, stream>>>(ctx, tgt, lens, sel, out);
}

// Round 6
// 363.187 us; speedup vs baseline: 1.0610x; 1.0393x over previous
//
#include <hip/hip_runtime.h>
#include <hip/hip_bf16.h>
#include <stdint.h>

// Problem constants (from reference setup_inputs)
//
// Dtype facts — established by controlled comparison R1..R4:
//   inputs = float32, outputs = float32 (wc [B,D] then attn [B,S]).
// Timing facts (R5 counters): timed window is dominated by harness resets
//   (1 GiB ws poison ~160us + d_in restore ~90us); my 3 kernels < ~70us
//   total. K2's 256 MiB ctx stream (~40us at 6.3 TB/s) is the kernel floor.
#define BB   64
#define SS   2048
#define DD   512
#define NBLK 8

// load 8 consecutive f32 (two float4s); p must be 16B-aligned
__device__ __forceinline__ void load8f(const float* __restrict__ p, float* o) {
    const float4 a = ((const float4*)p)[0];
    const float4 b = ((const float4*)p)[1];
    o[0]=a.x; o[1]=a.y; o[2]=a.z; o[3]=a.w;
    o[4]=b.x; o[5]=b.y; o[6]=b.z; o[7]=b.w;
}

__device__ __forceinline__ float dot8f(const float* a, const float* t) {
    float acc = a[0] * t[0];
    #pragma unroll
    for (int i = 1; i < 8; ++i) acc = fmaf(a[i], t[i], acc);
    return acc;
}

__device__ __forceinline__ float wave_reduce_sum(float acc) {
    #pragma unroll
    for (int off = 32; off >= 1; off >>= 1)
        acc += __shfl_xor(acc, off, 64);
    return acc;
}

// ---------------------------------------------------------------------
// K1: target[b,i] = sum_k h[b,k] * W[i,k]  (h @ W.T), f32 -> tgt (ws).
// One wave computes 4 outputs; pairwise-fold reduction: 7 shfl / 4 rows.
// ---------------------------------------------------------------------
#define K1_IPW 4
__global__ __launch_bounds__(256) void sdba_k1_target(
        const float* __restrict__ h, const float* __restrict__ W,
        float* __restrict__ tgt) {
    const int wid  = (blockIdx.x * blockDim.x + threadIdx.x) >> 6;
    const int lane = threadIdx.x & 63;
    const int out0 = wid * K1_IPW;          // global index = b*DD + i0
    const int b    = out0 / DD;
    const int i0   = out0 - b * DD;

    float hf[8];
    load8f(h + (size_t)b * DD + lane * 8, hf);

    float acc[K1_IPW];
    #pragma unroll
    for (int r = 0; r < K1_IPW; ++r) {
        float wf[8];
        load8f(W + (size_t)(i0 + r) * DD + lane * 8, wf);
        acc[r] = dot8f(wf, hf);
    }

    // fold rows across lane bits 0..1; lane ends holding row (lane&3)
    float b2[2];
    {
        const int bit = lane & 1;
        #pragma unroll
        for (int j = 0; j < 2; ++j) {
            float keep = bit ? acc[2*j+1] : acc[2*j];
            float send = bit ? acc[2*j]   : acc[2*j+1];
            b2[j] = keep + __shfl_xor(send, 1, 64);
        }
    }
    float v;
    {
        const int bit = (lane >> 1) & 1;
        float keep = bit ? b2[1] : b2[0];
        float send = bit ? b2[0] : b2[1];
        v = keep + __shfl_xor(send, 2, 64);
    }
    v += __shfl_xor(v, 4, 64);
    v += __shfl_xor(v, 8, 64);
    v += __shfl_xor(v, 16, 64);
    v += __shfl_xor(v, 32, 64);

    if (lane < K1_IPW)
        tgt[(size_t)out0 + lane] = v;
}

// ---------------------------------------------------------------------
// K2 (fused): both halves depend only on tgt, not on each other.
//   blocks [0, BB)        : softmax + weighted-context for batch b
//                           (scheduled FIRST so they hide under the
//                            attn stream instead of serializing after)
//   blocks [BB, BB+g2)    : attn rows, 8 rows/wave, 2 KiB row loads,
//                           pairwise-fold reduction (10 shfl / 8 rows)
// ---------------------------------------------------------------------
#define K2_RPW 8
__global__ __launch_bounds__(256) void sdba_k2_fused(
        const float* __restrict__ ctx, const float* __restrict__ tgt,
        const int* __restrict__ lens, const int* __restrict__ sel,
        float* __restrict__ out_wc, float* __restrict__ attn_out) {
    const int lane = threadIdx.x & 63;
    const int wave = threadIdx.x >> 6;

    __shared__ float attn_s[64];
    __shared__ float p_s[64];
    __shared__ float red[4][DD];   // 8 KiB cross-wave reduction buffer

    if (blockIdx.x >= BB) {
        // ---------------- attn half ----------------
        const int wid  = ((blockIdx.x - BB) * blockDim.x + threadIdx.x) >> 6;
        const size_t row0 = (size_t)wid * K2_RPW;   // global row = b*SS + s
        const int b = (int)(row0 >> 11);            // / SS (2048)

        float t[8];
        load8f(tgt + (size_t)b * DD + lane * 8, t);

        const float* cbase = ctx + row0 * DD + (size_t)lane * 8;
        float acc[K2_RPW];
        #pragma unroll
        for (int r = 0; r < K2_RPW; ++r) {
            float cf[8];
            load8f(cbase + (size_t)r * DD, cf);
            acc[r] = dot8f(cf, t);
        }

        // fold rows across lane bits 0..2; lane ends holding row (lane&7)
        float b4[4];
        {
            const int bit = lane & 1;
            #pragma unroll
            for (int j = 0; j < 4; ++j) {
                float keep = bit ? acc[2*j+1] : acc[2*j];
                float send = bit ? acc[2*j]   : acc[2*j+1];
                b4[j] = keep + __shfl_xor(send, 1, 64);
            }
        }
        float b2[2];
        {
            const int bit = (lane >> 1) & 1;
            #pragma unroll
            for (int j = 0; j < 2; ++j) {
                float keep = bit ? b4[2*j+1] : b4[2*j];
                float send = bit ? b4[2*j]   : b4[2*j+1];
                b2[j] = keep + __shfl_xor(send, 2, 64);
            }
        }
        float v;
        {
            const int bit = (lane >> 2) & 1;
            float keep = bit ? b2[1] : b2[0];
            float send = bit ? b2[0] : b2[1];
            v = keep + __shfl_xor(send, 4, 64);
        }
        v += __shfl_xor(v, 8, 64);
        v += __shfl_xor(v, 16, 64);
        v += __shfl_xor(v, 32, 64);

        if (lane < K2_RPW)
            attn_out[row0 + lane] = v;
        return;
    }

    // ---------------- softmax + weighted-context half ----------------
    const int b   = blockIdx.x;
    const int tid = threadIdx.x;

    // selected-block boundaries: sc = excl-cumsum at sel + 1, L = lens[sel]
    const int sidx = sel[b];
    int start = 0;
    #pragma unroll
    for (int j = 0; j < NBLK; ++j) {
        int lj = lens[b * NBLK + j];
        if (j < sidx) start += lj;
    }
    const int L  = lens[b * NBLK + sidx];   // 1..63
    const int sc = start + 1;

    float t[8];
    load8f(tgt + (size_t)b * DD + lane * 8, t);

    // logits for the selected block rows (wave-parallel over rows)
    for (int s = wave; s < L; s += 4) {
        float cf[8];
        load8f(ctx + ((size_t)b * SS + sc + s) * DD + lane * 8, cf);
        float acc = dot8f(cf, t);
        acc = wave_reduce_sum(acc);
        if (lane == 0) attn_s[s] = acc;
    }
    __syncthreads();

    // softmax over L values (single wave; L <= 63)
    if (tid < 64) {
        const float v = (tid < L) ? attn_s[tid] : -INFINITY;
        float m = v;
        #pragma unroll
        for (int off = 32; off >= 1; off >>= 1)
            m = fmaxf(m, __shfl_xor(m, off, 64));
        const float e = (tid < L) ? __expf(v - m) : 0.f;
        float sum = e;
        #pragma unroll
        for (int off = 32; off >= 1; off >>= 1)
            sum += __shfl_xor(sum, off, 64);
        p_s[tid] = e / sum;
    }
    __syncthreads();

    // weighted_context[b,d] = sum_s p[s] * ctx[b, sc+s, d]
    // rows striped over 4 waves, 8 f32/lane, LDS cross-wave reduce
    float acc[8] = {0,0,0,0,0,0,0,0};
    for (int s = wave; s < L; s += 4) {
        float cf[8];
        load8f(ctx + ((size_t)b * SS + sc + s) * DD + lane * 8, cf);
        const float ps = p_s[s];
        #pragma unroll
        for (int j = 0; j < 8; ++j)
            acc[j] = fmaf(ps, cf[j], acc[j]);
    }
    #pragma unroll
    for (int j = 0; j < 8; ++j)
        red[wave][lane * 8 + j] = acc[j];
    __syncthreads();

    #pragma unroll
    for (int rep = 0; rep < 2; ++rep) {
        const int d = tid + rep * 256;
        const float v = red[0][d] + red[1][d] + red[2][d] + red[3][d];
        out_wc[(size_t)b * DD + d] = v;
    }
}

// ---------------------------------------------------------------------
extern "C" void kernel_launch(void* const* d_in, const int* in_sizes, int n_in,
                              void* d_out, int out_size, void* d_ws, size_t ws_size,
                              hipStream_t stream) {
    const float* h   = (const float*)d_in[0];  // [B, D]    f32
    const float* ctx = (const float*)d_in[1];  // [B, S, D] f32
    const float* W   = (const float*)d_in[2];  // [D, D]    f32
    const int* lens  = (const int*)d_in[3];    // [B, NB]   i32
    const int* sel   = (const int*)d_in[4];    // [B]       i32

    float* out      = (float*)d_out;           // wc [B,D] then attn [B,S], f32
    float* attn_out = out + (size_t)BB * DD;

    // target scratch: B*D f32 = 128 KiB in ws (fallback: wc region of
    // d_out — read by all fused-kernel blocks before wc writes land)
    float* tgt = (ws_size >= (size_t)BB * DD * 4) ? (float*)d_ws : out;

    const int g1 = (BB * DD / K1_IPW) / 4;   // 2048 blocks (4 waves/block)
    const int g2 = (BB * SS / K2_RPW) / 4;   // 4096 attn blocks

    sdba_k1_target<<<g1, 256, 0, stream>>>(h, W, tgt);
    sdba_k2_fused<<<BB + g2, 256, 0, stream>>>(ctx, tgt, lens, sel, out, attn_out);
}